// Round 13
// baseline (1970.115 us; speedup 1.0000x reference)
//
#include <hip/hip_runtime.h>
#include <hip/hip_cooperative_groups.h>

namespace cg = cooperative_groups;

typedef short bf16x8 __attribute__((ext_vector_type(8)));
typedef float f32x4 __attribute__((ext_vector_type(4)));

#define STREP 512
#define MB 1048576
#define SMSZ 24576

__device__ __forceinline__ float leaky_f(float z) { return fmaxf(z, 0.2f * z); }
__device__ __forceinline__ unsigned short f2b(float f) {
    unsigned u = __float_as_uint(f);
    return (unsigned short)((u + 0x7fffu + ((u >> 16) & 1u)) >> 16);  // RTNE
}
__device__ __forceinline__ float b2f(unsigned short h) {
    return __uint_as_float(((unsigned)h) << 16);
}

struct Pr {
    const float* x; const float* mm;
    const int* n0; const int* n1; const int* n2; const int* n3;
    const float* w[8]; const float* G[8]; const float* E[8];
    const float* wm; const float* bm; const float* wfc; const float* bfc;
    unsigned short *X0, *Y1, *Y2, *P1b, *Y21, *Y22, *P2b, *WPp, *F31, *F32, *P3b, *F41;
    float *Zb, *stb, *fcp, *outp;
};

// ---------------------------------------------------------------------------
// P0: zero stats+fcpart, cast x -> bf16 [V][4b][4ci], prepack all weights
// ---------------------------------------------------------------------------
__device__ void ph_init(const Pr& a, int grid) {
    const int stride = grid * 256;
    const int t0 = blockIdx.x * 256 + threadIdx.x;
    for (int i = t0; i < 32768 + 4096; i += stride) a.stb[i] = 0.f;
    for (int i = t0; i < 40962 * 16; i += stride) {
        int v = i >> 4, b = (i >> 2) & 3, ci = i & 3;
        a.X0[i] = f2b(a.x[(size_t)v * 16 + ci * 4 + b]);
    }
    for (int g = t0; g < 2514944; g += stride) {
        const float* W; int base, KC, NT;
        if (g < 3072)        { W = a.w[0]; base = 0;       KC = 76;   NT = 2; }
        else if (g < 22528)  { W = a.w[1]; base = 3072;    KC = 608;  NT = 2; }
        else if (g < 61440)  { W = a.w[2]; base = 22528;   KC = 608;  NT = 4; }
        else if (g < 139264) { W = a.w[3]; base = 61440;   KC = 1216; NT = 4; }
        else if (g < 303104) { W = a.w[4]; base = 139264;  KC = 1216; NT = 8; }
        else if (g < 614400) { W = a.w[5]; base = 303104;  KC = 2432; NT = 8; }
        else if (g < 1269760){ W = a.w[6]; base = 614400;  KC = 2432; NT = 16; }
        else                 { W = a.w[7]; base = 1269760; KC = 4864; NT = 16; }
        int idx = g - base;
        int j = idx & 7, lane = (idx >> 3) & 63, q = idx >> 9;
        int nt = q % NT, chunk = q / NT;
        int kc = chunk * 32 + (lane >> 4) * 8 + j;
        int cout = nt * 16 + (lane & 15);
        float v = (kc < KC) ? W[(size_t)cout * KC + kc] : 0.f;
        a.WPp[g] = f2b(v);
    }
}

// ---------------------------------------------------------------------------
// conv1_1: CIN=4, quad-tile (4v x 4b per wave); raw bf16 out + replicated stats
// ---------------------------------------------------------------------------
__device__ void ph_conv1(unsigned char* SM, const unsigned short* act,
                         const int* neigh, const unsigned short* wp,
                         unsigned short* y, float* strep, int grid) {
    const int tid = threadIdx.x, lane = tid & 63, wib = tid >> 6;
    int* sn = (int*)SM + wib * 76;                       // 4*76*4 = 1216
    float* ss = (float*)(SM + 1280);                     // 64 f
    unsigned short* est = (unsigned short*)(SM + 2048) + wib * 512;  // 4*512*2
    const int m = lane & 15, quad = lane >> 4;
    const int b = m & 3, vq = m >> 2;
    const unsigned short* wl = wp + (size_t)lane * 8;
    for (int t = tid; t < 64; t += 256) ss[t] = 0.f;
    __syncthreads();
    const int V = 40962, lim = V * 19 - 1;
    float slA[2] = {0.f, 0.f}, qlA[2] = {0.f, 0.f};
    for (int wk = blockIdx.x; wk < 2561; wk += grid) {
        const int v0 = (wk * 4 + wib) * 4;
        for (int t = lane; t < 76; t += 64) {
            int src = v0 * 19 + t;
            sn[t] = neigh[src < lim ? src : lim];
        }
        f32x4 acc[2] = {(f32x4){0.f,0.f,0.f,0.f}, (f32x4){0.f,0.f,0.f,0.f}};
        union { unsigned u[4]; bf16x8 v; } w[3];
        bf16x8 bfr[3][2];
#pragma unroll
        for (int ch = 0; ch < 3; ++ch) {
            int k0 = (ch * 32 + quad * 8) >> 2;
            int k0c = k0 < 18 ? k0 : 18;
            int k1c = k0 + 1 < 18 ? k0 + 1 : 18;
            const unsigned* p0 = (const unsigned*)(act + ((size_t)sn[vq * 19 + k0c] * 4 + b) * 4);
            const unsigned* p1 = (const unsigned*)(act + ((size_t)sn[vq * 19 + k1c] * 4 + b) * 4);
            w[ch].u[0] = p0[0]; w[ch].u[1] = p0[1];
            w[ch].u[2] = p1[0]; w[ch].u[3] = p1[1];   // OOB k: zero-padded weights
#pragma unroll
            for (int t = 0; t < 2; ++t)
                bfr[ch][t] = *(const bf16x8*)(wl + (size_t)ch * 1024 + (size_t)t * 512);
        }
        __builtin_amdgcn_sched_barrier(0);
#pragma unroll
        for (int ch = 0; ch < 3; ++ch)
#pragma unroll
            for (int t = 0; t < 2; ++t)
                acc[t] = __builtin_amdgcn_mfma_f32_16x16x32_bf16(w[ch].v, bfr[ch][t], acc[t], 0, 0, 0);
        const bool valid = (v0 + quad < V);
#pragma unroll
        for (int r = 0; r < 4; ++r)
#pragma unroll
            for (int t = 0; t < 2; ++t) {
                float val = acc[t][r];
                est[(quad * 4 + r) * 32 + t * 16 + m] = f2b(val);
                if (valid) { slA[t] += val; qlA[t] = fmaf(val, val, qlA[t]); }
            }
        {   // coalesced store (wave-private est)
            const int seg = lane >> 2, sub = lane & 3;
            const int vl = seg >> 2, bs = seg & 3;
            const int v = v0 + vl;
            if (v < V)
                *(uint4*)(y + ((size_t)v * 4 + bs) * 32 + sub * 8) =
                    *(const uint4*)(est + seg * 32 + sub * 8);
        }
    }
#pragma unroll
    for (int t = 0; t < 2; ++t) {
        atomicAdd(&ss[t * 16 + m], slA[t]);
        atomicAdd(&ss[32 + t * 16 + m], qlA[t]);
    }
    __syncthreads();
    float* orep = strep + (blockIdx.x & 7) * STREP;
    for (int t = tid; t < 64; t += 256) atomicAdd(&orep[t], ss[t]);
}

// ---------------------------------------------------------------------------
// FUSE conv (levels 1-2): wave = 16v x 2b (two M-tiles sharing B-fragments);
// pair p=xcd>>2 pinned; BN at gather from replicated prev stats; coalesced
// bf16 stores; replicated output stats via global atomics.
// ---------------------------------------------------------------------------
template <int CIN, int NG, int CPS, bool BN>
__device__ void ph_conv_fuse(unsigned char* SM, const unsigned short* act,
                             const int* neigh, const unsigned short* wp,
                             unsigned short* y, float* strep_out,
                             const float* strep_in, const float* pg,
                             const float* pe, float invN, int V, int grid) {
    constexpr int COUT = NG * 16;
    constexpr int LOGC = (CIN == 32) ? 5 : 6;
    constexpr int GP = (NG >= 4) ? 2 : 4;
    constexpr int NGR = (CPS + GP - 1) / GP;
    const int tid = threadIdx.x, lane = tid & 63, wib = tid >> 6;
    int* sn = (int*)SM + wib * 304;                       // 4864 B
    float* ss = (float*)(SM + 4864);                      // <=512 B
    float2* lac = (float2*)(SM + 5888);                   // <=512 B
    unsigned short* est = (unsigned short*)(SM + 8192) + wib * 32 * COUT;
    const int m = lane & 15, quad = lane >> 4;
    const int vi = m >> 1, bb = m & 1;
    const int xcd = blockIdx.x & 7, p = xcd >> 2;
    const int perX = grid >> 3;
    const int S = perX * 4;
    const int slot = (xcd & 3) * perX + (blockIdx.x >> 3);
    for (int t = tid; t < 2 * COUT; t += 256) ss[t] = 0.f;
    if constexpr (BN) {
        for (int c = tid; c < CIN; c += 256) {
            float s = 0.f, q = 0.f;
#pragma unroll
            for (int k = 0; k < 8; ++k) { s += strep_in[k * STREP + c]; q += strep_in[k * STREP + CIN + c]; }
            float mu = s * invN;
            float var = fmaf(q, invN, -mu * mu);
            float aa = pg[c] * rsqrtf(var + 1e-5f);
            lac[c] = make_float2(aa, fmaf(-mu, aa, pe[c]));
        }
    }
    __syncthreads();
    const unsigned short* wl = wp + (size_t)lane * 8;
    const int boff = p * 2 + bb;
    const int T16 = (V + 15) >> 4, ST = (T16 + 3) >> 2, lim = V * 19 - 1;
    float slA[NG], qlA[NG];
#pragma unroll
    for (int t = 0; t < NG; ++t) { slA[t] = 0.f; qlA[t] = 0.f; }
    for (int li = slot; li < ST; li += S) {
        const int v0 = (li * 4 + wib) * 16;
        for (int t = lane; t < 304; t += 64) {
            int src = v0 * 19 + t;
            sn[t] = neigh[src < lim ? src : lim];
        }
        f32x4 acc[2][NG];
#pragma unroll
        for (int h = 0; h < 2; ++h)
#pragma unroll
            for (int t = 0; t < NG; ++t) acc[h][t] = (f32x4){0.f,0.f,0.f,0.f};
#pragma unroll
        for (int gi = 0; gi < NGR; ++gi) {
            bf16x8 A[2][GP];
            bf16x8 Bf[GP][NG];
            int cia[GP];
#pragma unroll
            for (int g = 0; g < GP; ++g) {
                const int ch = gi * GP + g;
                if (ch < CPS) {
                    int k_nb = (ch * 32) >> LOGC;
                    k_nb = k_nb < 18 ? k_nb : 18;
                    const int ci = ((ch * 32) & (CIN - 1)) + quad * 8;
                    cia[g] = ci;
#pragma unroll
                    for (int h = 0; h < 2; ++h) {
                        const int n = sn[(h * 8 + vi) * 19 + k_nb];
                        A[h][g] = *(const bf16x8*)(act + ((size_t)n * 4 + boff) * CIN + ci);
                    }
                    const unsigned short* wc = wl + (size_t)ch * NG * 512;
#pragma unroll
                    for (int t = 0; t < NG; ++t)
                        Bf[g][t] = *(const bf16x8*)(wc + (size_t)t * 512);
                }
            }
            __builtin_amdgcn_sched_barrier(0);
            if constexpr (BN) {
#pragma unroll
                for (int g = 0; g < GP; ++g) {
                    if (gi * GP + g < CPS) {
#pragma unroll
                        for (int h = 0; h < 2; ++h) {
                            bf16x8 r = A[h][g];
#pragma unroll
                            for (int j = 0; j < 8; ++j) {
                                float2 t2 = lac[cia[g] + j];
                                r[j] = (short)f2b(leaky_f(fmaf(b2f((unsigned short)r[j]), t2.x, t2.y)));
                            }
                            A[h][g] = r;
                        }
                    }
                }
            }
#pragma unroll
            for (int g = 0; g < GP; ++g) {
                if (gi * GP + g < CPS) {
#pragma unroll
                    for (int t = 0; t < NG; ++t) {
                        acc[0][t] = __builtin_amdgcn_mfma_f32_16x16x32_bf16(A[0][g], Bf[g][t], acc[0][t], 0, 0, 0);
                        acc[1][t] = __builtin_amdgcn_mfma_f32_16x16x32_bf16(A[1][g], Bf[g][t], acc[1][t], 0, 0, 0);
                    }
                }
            }
        }
        // epilogue: est + stats
#pragma unroll
        for (int h = 0; h < 2; ++h)
#pragma unroll
            for (int r = 0; r < 4; ++r) {
                const int vl2 = quad * 2 + (r >> 1);
                const int v = v0 + h * 8 + vl2;
                const int seg = h * 16 + vl2 * 2 + (r & 1);
                const bool valid = (v < V);
#pragma unroll
                for (int t = 0; t < NG; ++t) {
                    float val = acc[h][t][r];
                    est[seg * COUT + t * 16 + m] = f2b(val);
                    if (valid) { slA[t] += val; qlA[t] = fmaf(val, val, qlA[t]); }
                }
            }
        {   // coalesced store (wave-private est): 32 segs, 2 lanes/seg
            const int seg2 = lane >> 1, sub2 = lane & 1;
            const int h = seg2 >> 4, rem = seg2 & 15;
            const int vl = rem >> 1, bst = rem & 1;
            const int v = v0 + h * 8 + vl;
            if (v < V) {
                const unsigned short* src = est + seg2 * COUT + sub2 * (COUT / 2);
                unsigned short* dst = y + ((size_t)v * 4 + p * 2 + bst) * COUT + sub2 * (COUT / 2);
#pragma unroll
                for (int j = 0; j < NG; ++j)
                    *(uint4*)(dst + j * 8) = *(const uint4*)(src + j * 8);
            }
        }
    }
#pragma unroll
    for (int t = 0; t < NG; ++t) {
        atomicAdd(&ss[t * 16 + m], slA[t]);
        atomicAdd(&ss[COUT + t * 16 + m], qlA[t]);
    }
    __syncthreads();
    float* orep = strep_out + (blockIdx.x & 7) * STREP;
    for (int t = tid; t < 2 * COUT; t += 256) atomicAdd(&orep[t], ss[t]);
}

// ---------------------------------------------------------------------------
// Split-K conv (levels 3-4): 8v x 2b tiles, per-SPLIT output buffers,
// coalesced fp32 stores via wave-private LDS. No stats here.
// ---------------------------------------------------------------------------
template <int CIN, int COUT, int CPS, int SPLIT>
__device__ void ph_conv_split(unsigned char* SM, const unsigned short* act,
                              const int* neigh, const unsigned short* wp,
                              float* Z, int V, int sstr, int grid) {
    constexpr int LOGC = (CIN == 64) ? 6 : (CIN == 128) ? 7 : 8;
    constexpr int NG = 4;
    constexpr int NT = COUT / 16;
    constexpr int NGRP = NT / NG;
    constexpr int GP = 2;
    constexpr int NGR = (CPS + GP - 1) / GP;
    const int tid = threadIdx.x, lane = tid & 63, wib = tid >> 6;
    int* sn = (int*)SM + wib * 152;                 // 2432 B
    float* est = (float*)(SM + 2560) + wib * 1024;  // 4*16*64*4 B
    const int m = lane & 15, quad = lane >> 4;
    const int vi = m >> 1, bb = m & 1;
    const int xcd = blockIdx.x & 7, p = xcd >> 2;
    const int perX = grid >> 3;
    const int S = perX * 4;
    const int slot = (xcd & 3) * perX + (blockIdx.x >> 3);
    const unsigned short* wlb = wp + (size_t)lane * 8;
    const int boff = p * 2 + bb;
    const int T8 = (V + 7) >> 3, ST8 = (T8 + 3) >> 2;
    const int L = ST8 * NGRP * SPLIT, lim = V * 19 - 1;
    for (int li = slot; li < L; li += S) {
        const int sp = li % SPLIT;
        const int t1 = li / SPLIT;
        const int ng = t1 % NGRP;
        const int stile = t1 / NGRP;
        const int v0 = (stile * 4 + wib) * 8;
        for (int t = lane; t < 152; t += 64) {
            int src = v0 * 19 + t;
            sn[t] = neigh[src < lim ? src : lim];
        }
        const unsigned short* wl = wlb + (size_t)(ng * NG) * 64 * 8;
        const int c0 = sp * CPS;
        f32x4 acc[NG];
#pragma unroll
        for (int t = 0; t < NG; ++t) acc[t] = (f32x4){0.f,0.f,0.f,0.f};
#pragma unroll
        for (int gi = 0; gi < NGR; ++gi) {
            bf16x8 A[GP];
            bf16x8 Bf[GP][NG];
#pragma unroll
            for (int g = 0; g < GP; ++g) {
                const int chl = gi * GP + g;
                if (chl < CPS) {
                    const int ch = c0 + chl;
                    int k_nb = (ch * 32) >> LOGC;
                    k_nb = k_nb < 18 ? k_nb : 18;
                    const int ci = ((ch * 32) & (CIN - 1)) + quad * 8;
                    const int n = sn[vi * 19 + k_nb];
                    A[g] = *(const bf16x8*)(act + ((size_t)n * 4 + boff) * CIN + ci);
                    const unsigned short* wc = wl + (size_t)ch * NT * 512;
#pragma unroll
                    for (int t = 0; t < NG; ++t)
                        Bf[g][t] = *(const bf16x8*)(wc + (size_t)t * 512);
                }
            }
            __builtin_amdgcn_sched_barrier(0);
#pragma unroll
            for (int g = 0; g < GP; ++g) {
                if (gi * GP + g < CPS) {
#pragma unroll
                    for (int t = 0; t < NG; ++t)
                        acc[t] = __builtin_amdgcn_mfma_f32_16x16x32_bf16(A[g], Bf[g][t], acc[t], 0, 0, 0);
                }
            }
        }
#pragma unroll
        for (int r = 0; r < 4; ++r) {
            const int vl2 = quad * 2 + (r >> 1);
            const int seg = vl2 * 2 + (r & 1);
#pragma unroll
            for (int t = 0; t < NG; ++t)
                est[seg * 64 + t * 16 + m] = acc[t][r];
        }
        {
            float* yb = Z + (size_t)sp * sstr;
            const int seg = lane >> 2, sub = lane & 3;
            const int vl = seg >> 1, bst = seg & 1;
            const int v = v0 + vl;
            if (v < V) {
                const float* src = est + seg * 64 + sub * 16;
                float* dst = yb + ((size_t)v * 4 + p * 2 + bst) * COUT + ng * 64 + sub * 16;
#pragma unroll
                for (int j = 0; j < 4; ++j)
                    *(float4*)(dst + j * 4) = *(const float4*)(src + j * 4);
            }
        }
    }
}

// ---------------------------------------------------------------------------
// stats over NS split buffers -> replicated stats
// ---------------------------------------------------------------------------
template <int C, int NS>
__device__ void ph_stats_split(unsigned char* SM, const float* y, float* strep,
                               int rows, int sstr, int grid) {
    constexpr int LOGC = (C == 128) ? 7 : 8;
    float* ss = (float*)SM;
    const int tid = threadIdx.x;
    for (int i = tid; i < 2 * C; i += 256) ss[i] = 0.f;
    __syncthreads();
    const int c = tid & (C - 1);
    const int rpb = 256 >> LOGC;
    float s = 0.f, q = 0.f;
    for (int r = blockIdx.x * rpb + (tid >> LOGC); r < rows; r += grid * rpb) {
        float v = 0.f;
#pragma unroll
        for (int k = 0; k < NS; ++k) v += y[(size_t)k * sstr + (size_t)r * C + c];
        s += v;
        q = fmaf(v, v, q);
    }
    atomicAdd(&ss[c], s);
    atomicAdd(&ss[C + c], q);
    __syncthreads();
    float* orep = strep + (blockIdx.x & 7) * STREP;
    for (int i = tid; i < 2 * C; i += 256) atomicAdd(&orep[i], ss[i]);
}

// ---------------------------------------------------------------------------
// bnleaky(sum of NS splits) -> finished bf16
// ---------------------------------------------------------------------------
template <int C, int NS>
__device__ void ph_finalize_split(unsigned char* SM, const float* yin,
                                  const float* strep, const float* g,
                                  const float* be, float invN,
                                  unsigned short* out, int total4, int sstr, int grid) {
    float* la = (float*)SM;
    float* lc = la + C;
    const int tid = threadIdx.x;
    for (int c = tid; c < C; c += 256) {
        float s = 0.f, q = 0.f;
#pragma unroll
        for (int k = 0; k < 8; ++k) { s += strep[k * STREP + c]; q += strep[k * STREP + C + c]; }
        float mu = s * invN;
        float var = fmaf(q, invN, -mu * mu);
        float aa = g[c] * rsqrtf(var + 1e-5f);
        la[c] = aa;
        lc[c] = fmaf(-mu, aa, be[c]);
    }
    __syncthreads();
    for (int idx = blockIdx.x * 256 + tid; idx < total4; idx += grid * 256) {
        int c0 = (idx * 4) & (C - 1);
        float4 yv = make_float4(0.f, 0.f, 0.f, 0.f);
#pragma unroll
        for (int k = 0; k < NS; ++k) {
            float4 t = *(const float4*)(yin + (size_t)k * sstr + (size_t)idx * 4);
            yv.x += t.x; yv.y += t.y; yv.z += t.z; yv.w += t.w;
        }
        float o0 = leaky_f(fmaf(la[c0 + 0], yv.x, lc[c0 + 0]));
        float o1 = leaky_f(fmaf(la[c0 + 1], yv.y, lc[c0 + 1]));
        float o2 = leaky_f(fmaf(la[c0 + 2], yv.z, lc[c0 + 2]));
        float o3 = leaky_f(fmaf(la[c0 + 3], yv.w, lc[c0 + 3]));
        unsigned r0 = (unsigned)f2b(o0) | ((unsigned)f2b(o1) << 16);
        unsigned r1 = (unsigned)f2b(o2) | ((unsigned)f2b(o3) << 16);
        ((uint2*)out)[idx] = make_uint2(r0, r1);
    }
}

// ---------------------------------------------------------------------------
// mean-pool [Vin][4][C] -> [VP][4][C]; BN from replicated producer stats
// ---------------------------------------------------------------------------
template <int C, bool BN>
__device__ void ph_pool(unsigned char* SM, const unsigned short* in,
                        const int* neigh, const float* strep, const float* pg,
                        const float* pe, float invN, unsigned short* out,
                        int total, int grid) {
    constexpr int LC4 = (C == 32) ? 3 : (C == 64) ? 4 : 5;
    float2* lac = (float2*)SM;
    const int tid = threadIdx.x;
    if constexpr (BN) {
        for (int c = tid; c < C; c += 256) {
            float s = 0.f, q = 0.f;
#pragma unroll
            for (int k = 0; k < 8; ++k) { s += strep[k * STREP + c]; q += strep[k * STREP + C + c]; }
            float mu = s * invN;
            float var = fmaf(q, invN, -mu * mu);
            float aa = pg[c] * rsqrtf(var + 1e-5f);
            lac[c] = make_float2(aa, fmaf(-mu, aa, pe[c]));
        }
        __syncthreads();
    }
    for (int idx = blockIdx.x * 256 + tid; idx < total; idx += grid * 256) {
        int c4 = idx & ((C / 4) - 1);
        int b = (idx >> LC4) & 3;
        int vp = idx >> (LC4 + 2);
        float a0 = 0.f, a1 = 0.f, a2 = 0.f, a3 = 0.f;
        for (int k = 0; k < 19; ++k) {
            int n = neigh[vp * 19 + k];
            uint2 d = *(const uint2*)(in + ((size_t)n * 4 + b) * C + c4 * 4);
            float f0 = b2f((unsigned short)(d.x & 0xffff));
            float f1 = b2f((unsigned short)(d.x >> 16));
            float f2 = b2f((unsigned short)(d.y & 0xffff));
            float f3 = b2f((unsigned short)(d.y >> 16));
            if constexpr (BN) {
                float2 t0 = lac[c4 * 4 + 0], t1 = lac[c4 * 4 + 1];
                float2 t2 = lac[c4 * 4 + 2], t3 = lac[c4 * 4 + 3];
                f0 = leaky_f(fmaf(f0, t0.x, t0.y));
                f1 = leaky_f(fmaf(f1, t1.x, t1.y));
                f2 = leaky_f(fmaf(f2, t2.x, t2.y));
                f3 = leaky_f(fmaf(f3, t3.x, t3.y));
            }
            a0 += f0; a1 += f1; a2 += f2; a3 += f3;
        }
        const float r = 1.f / 19.f;
        unsigned r0 = (unsigned)f2b(a0 * r) | ((unsigned)f2b(a1 * r) << 16);
        unsigned r1 = (unsigned)f2b(a2 * r) | ((unsigned)f2b(a3 * r) << 16);
        ((uint2*)out)[idx] = make_uint2(r0, r1);
    }
}

// ---------------------------------------------------------------------------
// FC partial over bnleaky(sum of 8 splits of y4_2 [642][4][256])
// ---------------------------------------------------------------------------
__device__ void ph_fc_partial(unsigned char* SM, const float* y, const float* wfc,
                              const float* strep, const float* g, const float* be,
                              float invN, float* fcpart, int sstr, int grid) {
    float* la = (float*)SM;
    float* lc = la + 256;
    float* sh = lc + 256;
    const int tid = threadIdx.x;
    if (tid < 4) sh[tid] = 0.f;
    {
        int c = tid;
        float s = 0.f, q = 0.f;
#pragma unroll
        for (int k = 0; k < 8; ++k) { s += strep[k * STREP + c]; q += strep[k * STREP + 256 + c]; }
        float mu = s * invN;
        float var = fmaf(q, invN, -mu * mu);
        float aa = g[c] * rsqrtf(var + 1e-5f);
        la[c] = aa;
        lc[c] = fmaf(-mu, aa, be[c]);
    }
    __syncthreads();
    float p0 = 0.f, p1 = 0.f, p2 = 0.f, p3 = 0.f;
    const int VC = 642 * 256;
    for (int idx = blockIdx.x * 256 + tid; idx < VC; idx += grid * 256) {
        int c = idx & 255;
        float aa = la[c], cc = lc[c];
        float w = wfc[idx];
        size_t base = ((size_t)(idx >> 8) << 10) + c;
        float y0 = 0.f, y1 = 0.f, y2 = 0.f, y3 = 0.f;
#pragma unroll
        for (int k = 0; k < 8; ++k) {
            const float* yk = y + (size_t)k * sstr;
            y0 += yk[base]; y1 += yk[base + 256]; y2 += yk[base + 512]; y3 += yk[base + 768];
        }
        p0 = fmaf(w, leaky_f(fmaf(aa, y0, cc)), p0);
        p1 = fmaf(w, leaky_f(fmaf(aa, y1, cc)), p1);
        p2 = fmaf(w, leaky_f(fmaf(aa, y2, cc)), p2);
        p3 = fmaf(w, leaky_f(fmaf(aa, y3, cc)), p3);
    }
    atomicAdd(&sh[0], p0);
    atomicAdd(&sh[1], p1);
    atomicAdd(&sh[2], p2);
    atomicAdd(&sh[3], p3);
    __syncthreads();
    if (tid < 4) fcpart[blockIdx.x * 4 + tid] = sh[tid];
}

__device__ void ph_fc_final(const float* fcpart, const float* m, const float* wm,
                            const float* bm, const float* wfc, const float* bfc,
                            float* out, int grid) {
    if (blockIdx.x == 0 && threadIdx.x < 4) {
        int b = threadIdx.x;
        float acc = 0.f;
        for (int i = 0; i < grid; ++i) acc += fcpart[i * 4 + b];
        float mv = m[b];
        float s = 0.f;
#pragma unroll
        for (int j = 0; j < 4; ++j) {
            float mmv = fmaxf(fmaf(mv, wm[j], bm[j]), 0.f);
            s = fmaf(mmv, wfc[642 * 256 + j], s);
        }
        out[b] = acc + s + bfc[0];
    }
}

#define IN1 (1.f / 163848.f)
#define IN2 (1.f / 40968.f)
#define IN3 (1.f / 10248.f)
#define IN4 (1.f / 2568.f)
#define SSTR3 (2562 * 4 * 128)
#define SSTR4 (642 * 4 * 256)

// ---------------------------------------------------------------------------
// Single cooperative kernel: all phases, grid.sync between dependent ones.
// ---------------------------------------------------------------------------
__global__ __launch_bounds__(256, 4) void uber(Pr a, int grid) {
    __shared__ __align__(16) unsigned char SM[SMSZ];
    cg::grid_group gg = cg::this_grid();
    ph_init(a, grid); gg.sync();
    ph_conv1(SM, a.X0, a.n0, a.WPp, a.Y1, a.stb, grid); gg.sync();
    ph_conv_fuse<32, 2, 19, true>(SM, a.Y1, a.n0, a.WPp + 3072, a.Y2,
        a.stb + 4096, a.stb, a.G[0], a.E[0], IN1, 40962, grid); gg.sync();
    ph_pool<32, true>(SM, a.Y2, a.n0, a.stb + 4096, a.G[1], a.E[1], IN1,
        a.P1b, 10242 * 4 * 8, grid); gg.sync();
    ph_conv_fuse<32, 4, 19, false>(SM, a.P1b, a.n1, a.WPp + 22528, a.Y21,
        a.stb + 2 * 4096, nullptr, nullptr, nullptr, 0.f, 10242, grid); gg.sync();
    ph_conv_fuse<64, 4, 38, true>(SM, a.Y21, a.n1, a.WPp + 61440, a.Y22,
        a.stb + 3 * 4096, a.stb + 2 * 4096, a.G[2], a.E[2], IN2, 10242, grid); gg.sync();
    ph_pool<64, true>(SM, a.Y22, a.n1, a.stb + 3 * 4096, a.G[3], a.E[3], IN2,
        a.P2b, 2562 * 4 * 16, grid); gg.sync();
    ph_conv_split<64, 128, 10, 4>(SM, a.P2b, a.n2, a.WPp + 139264, a.Zb,
        2562, SSTR3, grid); gg.sync();
    ph_stats_split<128, 4>(SM, a.Zb, a.stb + 4 * 4096, 10248, SSTR3, grid); gg.sync();
    ph_finalize_split<128, 4>(SM, a.Zb, a.stb + 4 * 4096, a.G[4], a.E[4], IN3,
        a.F31, 327936, SSTR3, grid); gg.sync();
    ph_conv_split<128, 128, 19, 4>(SM, a.F31, a.n2, a.WPp + 303104, a.Zb,
        2562, SSTR3, grid); gg.sync();
    ph_stats_split<128, 4>(SM, a.Zb, a.stb + 5 * 4096, 10248, SSTR3, grid); gg.sync();
    ph_finalize_split<128, 4>(SM, a.Zb, a.stb + 5 * 4096, a.G[5], a.E[5], IN3,
        a.F32, 327936, SSTR3, grid); gg.sync();
    ph_pool<128, false>(SM, a.F32, a.n2, nullptr, nullptr, nullptr, 0.f,
        a.P3b, 642 * 4 * 32, grid); gg.sync();
    ph_conv_split<128, 256, 10, 8>(SM, a.P3b, a.n3, a.WPp + 614400, a.Zb,
        642, SSTR4, grid); gg.sync();
    ph_stats_split<256, 8>(SM, a.Zb, a.stb + 6 * 4096, 2568, SSTR4, grid); gg.sync();
    ph_finalize_split<256, 8>(SM, a.Zb, a.stb + 6 * 4096, a.G[6], a.E[6], IN4,
        a.F41, 164352, SSTR4, grid); gg.sync();
    ph_conv_split<256, 256, 19, 8>(SM, a.F41, a.n3, a.WPp + 1269760, a.Zb,
        642, SSTR4, grid); gg.sync();
    ph_stats_split<256, 8>(SM, a.Zb, a.stb + 7 * 4096, 2568, SSTR4, grid); gg.sync();
    ph_fc_partial(SM, a.Zb, a.wfc, a.stb + 7 * 4096, a.G[7], a.E[7], IN4,
        a.fcp, SSTR4, grid); gg.sync();
    ph_fc_final(a.fcp, a.mm, a.wm, a.bm, a.wfc, a.bfc, a.outp, grid);
}

// --------------------- fallback (non-cooperative) wrappers ------------------
__global__ __launch_bounds__(256, 4) void k_init(Pr a, int grid) { ph_init(a, grid); }
__global__ __launch_bounds__(256, 4) void k_conv1(Pr a, int grid) {
    __shared__ __align__(16) unsigned char SM[SMSZ];
    ph_conv1(SM, a.X0, a.n0, a.WPp, a.Y1, a.stb, grid);
}
template <int CIN, int NG, int CPS, bool BN>
__global__ __launch_bounds__(256, 4) void k_fuse(const unsigned short* act, const int* nb,
    const unsigned short* wp, unsigned short* y, float* so, const float* si,
    const float* pg, const float* pe, float invN, int V, int grid) {
    __shared__ __align__(16) unsigned char SM[SMSZ];
    ph_conv_fuse<CIN, NG, CPS, BN>(SM, act, nb, wp, y, so, si, pg, pe, invN, V, grid);
}
template <int CIN, int COUT, int CPS, int SPLIT>
__global__ __launch_bounds__(256, 4) void k_split(const unsigned short* act, const int* nb,
    const unsigned short* wp, float* Z, int V, int sstr, int grid) {
    __shared__ __align__(16) unsigned char SM[SMSZ];
    ph_conv_split<CIN, COUT, CPS, SPLIT>(SM, act, nb, wp, Z, V, sstr, grid);
}
template <int C, int NS>
__global__ __launch_bounds__(256, 4) void k_stats(const float* y, float* st, int rows,
                                                  int sstr, int grid) {
    __shared__ __align__(16) unsigned char SM[4096];
    ph_stats_split<C, NS>(SM, y, st, rows, sstr, grid);
}
template <int C, int NS>
__global__ __launch_bounds__(256, 4) void k_fin(const float* y, const float* st,
    const float* g, const float* be, float invN, unsigned short* out, int total4,
    int sstr, int grid) {
    __shared__ __align__(16) unsigned char SM[4096];
    ph_finalize_split<C, NS>(SM, y, st, g, be, invN, out, total4, sstr, grid);
}
template <int C, bool BN>
__global__ __launch_bounds__(256, 4) void k_pool(const unsigned short* in, const int* nb,
    const float* st, const float* pg, const float* pe, float invN,
    unsigned short* out, int total, int grid) {
    __shared__ __align__(16) unsigned char SM[4096];
    ph_pool<C, BN>(SM, in, nb, st, pg, pe, invN, out, total, grid);
}
__global__ __launch_bounds__(256, 4) void k_fcp(const float* y, const float* wfc,
    const float* st, const float* g, const float* be, float invN, float* fcpart,
    int sstr, int grid) {
    __shared__ __align__(16) unsigned char SM[4096];
    ph_fc_partial(SM, y, wfc, st, g, be, invN, fcpart, sstr, grid);
}
__global__ void k_fcf(const float* fcpart, const float* m, const float* wm,
                      const float* bm, const float* wfc, const float* bfc,
                      float* out, int grid) {
    ph_fc_final(fcpart, m, wm, bm, wfc, bfc, out, grid);
}

extern "C" void kernel_launch(void* const* d_in, const int* in_sizes, int n_in,
                              void* d_out, int out_size, void* d_ws, size_t ws_size,
                              hipStream_t stream) {
    Pr a;
    a.x  = (const float*)d_in[0];
    a.mm = (const float*)d_in[1];
    a.n0 = (const int*)d_in[2];
    a.n1 = (const int*)d_in[3];
    a.n2 = (const int*)d_in[4];
    a.n3 = (const int*)d_in[5];
    for (int k = 0; k < 8; ++k) {
        a.w[k] = (const float*)d_in[6 + 4 * k];
        // conv biases (d_in[7+4k]) cancel exactly through batch-stats BN
        a.G[k] = (const float*)d_in[8 + 4 * k];
        a.E[k] = (const float*)d_in[9 + 4 * k];
    }
    a.wm  = (const float*)d_in[38];
    a.bm  = (const float*)d_in[39];
    a.wfc = (const float*)d_in[40];
    a.bfc = (const float*)d_in[41];

    char* wsb = (char*)d_ws;
    a.X0  = (unsigned short*)(wsb + 0 * MB);
    a.Y1  = (unsigned short*)(wsb + 2 * MB);
    a.Y2  = (unsigned short*)(wsb + 13 * MB);
    a.P1b = (unsigned short*)(wsb + 24 * MB);
    a.Y21 = (unsigned short*)(wsb + 27 * MB);
    a.Y22 = (unsigned short*)(wsb + 33 * MB);
    a.P2b = (unsigned short*)(wsb + 39 * MB);
    a.WPp = (unsigned short*)(wsb + 41 * MB);
    a.Zb  = (float*)(wsb + 49 * MB);
    a.F31 = (unsigned short*)(wsb + 70 * MB);
    a.F32 = (unsigned short*)(wsb + 73 * MB);
    a.P3b = (unsigned short*)(wsb + 76 * MB);
    a.F41 = (unsigned short*)(wsb + 77 * MB);
    a.stb = (float*)(wsb + 79 * MB);
    a.fcp = a.stb + 32768;
    a.outp = (float*)d_out;

    int occ = 0;
    hipError_t qe = hipOccupancyMaxActiveBlocksPerMultiprocessor(&occ, uber, 256, 0);
    int grid = (qe == hipSuccess && occ > 0) ? occ * 256 : 0;
    if (grid > 1024) grid = 1024;
    grid &= ~7;

    bool done = false;
    if (grid >= 8) {
        void* kargs[2] = {(void*)&a, (void*)&grid};
        hipError_t le = hipLaunchCooperativeKernel((void*)uber, dim3(grid), dim3(256),
                                                   kargs, 0, stream);
        if (le == hipSuccess) done = true;
        else (void)hipGetLastError();
    }
    if (!done) {
        const int g = 1024;
        k_init<<<g, 256, 0, stream>>>(a, g);
        k_conv1<<<g, 256, 0, stream>>>(a, g);
        k_fuse<32, 2, 19, true><<<g, 256, 0, stream>>>(a.Y1, a.n0, a.WPp + 3072, a.Y2,
            a.stb + 4096, a.stb, a.G[0], a.E[0], IN1, 40962, g);
        k_pool<32, true><<<g, 256, 0, stream>>>(a.Y2, a.n0, a.stb + 4096, a.G[1], a.E[1],
            IN1, a.P1b, 10242 * 4 * 8, g);
        k_fuse<32, 4, 19, false><<<g, 256, 0, stream>>>(a.P1b, a.n1, a.WPp + 22528, a.Y21,
            a.stb + 2 * 4096, nullptr, nullptr, nullptr, 0.f, 10242, g);
        k_fuse<64, 4, 38, true><<<g, 256, 0, stream>>>(a.Y21, a.n1, a.WPp + 61440, a.Y22,
            a.stb + 3 * 4096, a.stb + 2 * 4096, a.G[2], a.E[2], IN2, 10242, g);
        k_pool<64, true><<<g, 256, 0, stream>>>(a.Y22, a.n1, a.stb + 3 * 4096, a.G[3],
            a.E[3], IN2, a.P2b, 2562 * 4 * 16, g);
        k_split<64, 128, 10, 4><<<g, 256, 0, stream>>>(a.P2b, a.n2, a.WPp + 139264, a.Zb,
            2562, SSTR3, g);
        k_stats<128, 4><<<g, 256, 0, stream>>>(a.Zb, a.stb + 4 * 4096, 10248, SSTR3, g);
        k_fin<128, 4><<<g, 256, 0, stream>>>(a.Zb, a.stb + 4 * 4096, a.G[4], a.E[4], IN3,
            a.F31, 327936, SSTR3, g);
        k_split<128, 128, 19, 4><<<g, 256, 0, stream>>>(a.F31, a.n2, a.WPp + 303104, a.Zb,
            2562, SSTR3, g);
        k_stats<128, 4><<<g, 256, 0, stream>>>(a.Zb, a.stb + 5 * 4096, 10248, SSTR3, g);
        k_fin<128, 4><<<g, 256, 0, stream>>>(a.Zb, a.stb + 5 * 4096, a.G[5], a.E[5], IN3,
            a.F32, 327936, SSTR3, g);
        k_pool<128, false><<<g, 256, 0, stream>>>(a.F32, a.n2, nullptr, nullptr, nullptr,
            0.f, a.P3b, 642 * 4 * 32, g);
        k_split<128, 256, 10, 8><<<g, 256, 0, stream>>>(a.P3b, a.n3, a.WPp + 614400, a.Zb,
            642, SSTR4, g);
        k_stats<256, 8><<<g, 256, 0, stream>>>(a.Zb, a.stb + 6 * 4096, 2568, SSTR4, g);
        k_fin<256, 8><<<g, 256, 0, stream>>>(a.Zb, a.stb + 6 * 4096, a.G[6], a.E[6], IN4,
            a.F41, 164352, SSTR4, g);
        k_split<256, 256, 19, 8><<<g, 256, 0, stream>>>(a.F41, a.n3, a.WPp + 1269760, a.Zb,
            642, SSTR4, g);
        k_stats<256, 8><<<g, 256, 0, stream>>>(a.Zb, a.stb + 7 * 4096, 2568, SSTR4, g);
        k_fcp<<<g, 256, 0, stream>>>(a.Zb, a.wfc, a.stb + 7 * 4096, a.G[7], a.E[7], IN4,
            a.fcp, SSTR4, g);
        k_fcf<<<1, 64, 0, stream>>>(a.fcp, a.mm, a.wm, a.bm, a.wfc, a.bfc, a.outp, g);
    }
}